// Round 1
// baseline (958.757 us; speedup 1.0000x reference)
//
#include <hip/hip_runtime.h>
#include <hip/hip_bf16.h>

#define HIDDEN 1024
#define HEADS 16
#define HEAD_DIM 64
#define SEQ 2048
#define BATCH 4

typedef __attribute__((ext_vector_type(8))) short bf16x8;
typedef __attribute__((ext_vector_type(4))) float f32x4;
typedef __attribute__((ext_vector_type(4))) short short4v;

static __device__ __forceinline__ unsigned short f2bf(float f) {
  union { float f; unsigned u; } u;
  u.f = f;
  unsigned r = u.u + 0x7fffu + ((u.u >> 16) & 1u);  // RTNE
  return (unsigned short)(r >> 16);
}

// ---------------- K0: W [K][N] fp32 -> Wt [N][K] bf16 (3 matrices) ----------
__global__ __launch_bounds__(256) void wtrans_kernel(
    const float* __restrict__ Wq, const float* __restrict__ Wk,
    const float* __restrict__ Wv, unsigned short* __restrict__ Wt) {
  __shared__ float tile[64][65];
  int z = blockIdx.z;
  const float* W = (z == 0) ? Wq : (z == 1) ? Wk : Wv;
  int k0 = blockIdx.x * 64, n0 = blockIdx.y * 64;
  int tid = threadIdx.x;
  int tr = tid >> 4;   // 0..15
  int tc = tid & 15;   // 0..15
#pragma unroll
  for (int p = 0; p < 4; ++p) {
    int kk = p * 16 + tr;
    float4 v = *(const float4*)(W + (size_t)(k0 + kk) * HIDDEN + n0 + tc * 4);
    tile[kk][tc * 4 + 0] = v.x; tile[kk][tc * 4 + 1] = v.y;
    tile[kk][tc * 4 + 2] = v.z; tile[kk][tc * 4 + 3] = v.w;
  }
  __syncthreads();
  unsigned short* op = Wt + (size_t)z * HIDDEN * HIDDEN;
#pragma unroll
  for (int p = 0; p < 4; ++p) {
    int nn = p * 16 + tr;
    short4v o;
    o.x = (short)f2bf(tile[tc * 4 + 0][nn]);
    o.y = (short)f2bf(tile[tc * 4 + 1][nn]);
    o.z = (short)f2bf(tile[tc * 4 + 2][nn]);
    o.w = (short)f2bf(tile[tc * 4 + 3][nn]);
    *(short4v*)(op + (size_t)(n0 + nn) * HIDDEN + k0 + tc * 4) = o;
  }
}

// ---------------- K1: LayerNorm: x -> out (xn fp32 residual), xnb (bf16) ----
__global__ __launch_bounds__(256) void ln_kernel(
    const float* __restrict__ x, const float* __restrict__ gamma,
    const float* __restrict__ beta, float* __restrict__ out,
    unsigned short* __restrict__ xnb) {
  int row = blockIdx.x;
  int tid = threadIdx.x;
  const float4* xr = (const float4*)(x + (size_t)row * HIDDEN);
  float4 v = xr[tid];
  float s = v.x + v.y + v.z + v.w;
  float sq = v.x * v.x + v.y * v.y + v.z * v.z + v.w * v.w;
#pragma unroll
  for (int off = 32; off >= 1; off >>= 1) {
    s += __shfl_xor(s, off);
    sq += __shfl_xor(sq, off);
  }
  __shared__ float red[8];
  int wave = tid >> 6, lane = tid & 63;
  if (lane == 0) { red[wave] = s; red[4 + wave] = sq; }
  __syncthreads();
  s = red[0] + red[1] + red[2] + red[3];
  sq = red[4] + red[5] + red[6] + red[7];
  float mu = s * (1.0f / HIDDEN);
  float var = sq * (1.0f / HIDDEN) - mu * mu;
  float rstd = rsqrtf(var + 1e-5f);
  float4 g = ((const float4*)gamma)[tid];
  float4 bt = ((const float4*)beta)[tid];
  float4 o;
  o.x = (v.x - mu) * rstd * g.x + bt.x;
  o.y = (v.y - mu) * rstd * g.y + bt.y;
  o.z = (v.z - mu) * rstd * g.z + bt.z;
  o.w = (v.w - mu) * rstd * g.w + bt.w;
  ((float4*)(out + (size_t)row * HIDDEN))[tid] = o;
  short4v p;
  p.x = (short)f2bf(o.x); p.y = (short)f2bf(o.y);
  p.z = (short)f2bf(o.z); p.w = (short)f2bf(o.w);
  *((short4v*)(xnb + (size_t)row * HIDDEN) + tid) = p;
}

// ---------------- K2: QKV GEMM: xnb[M,K] @ W[K,N] + b -> q/k bf16 [b,h,s,d],
//                  v transposed bf16 [b,h,d,s] ------------------------------
__global__ __launch_bounds__(256) void qkv_gemm(
    const unsigned short* __restrict__ xnb, const unsigned short* __restrict__ Wt,
    const float* __restrict__ bq, const float* __restrict__ bk,
    const float* __restrict__ bv, unsigned short* __restrict__ qO,
    unsigned short* __restrict__ kO, unsigned short* __restrict__ vtO) {
  int z = blockIdx.z;
  int m0 = blockIdx.x * 64;
  int n0 = blockIdx.y * 64;
  int tid = threadIdx.x;
  int wave = tid >> 6, lane = tid & 63;
  int lr = lane & 15, lk = (lane >> 4) * 8;
  const unsigned short* A = xnb + (size_t)(m0 + wave * 16 + lr) * HIDDEN + lk;
  const unsigned short* Bp = Wt + (size_t)z * HIDDEN * HIDDEN + (size_t)(n0 + lr) * HIDDEN + lk;
  f32x4 acc[4] = {{0,0,0,0},{0,0,0,0},{0,0,0,0},{0,0,0,0}};
  for (int k0 = 0; k0 < HIDDEN; k0 += 32) {
    bf16x8 aF = *(const bf16x8*)(A + k0);
#pragma unroll
    for (int nb = 0; nb < 4; ++nb) {
      bf16x8 bF = *(const bf16x8*)(Bp + (size_t)nb * 16 * HIDDEN + k0);
      acc[nb] = __builtin_amdgcn_mfma_f32_16x16x32_bf16(aF, bF, acc[nb], 0, 0, 0);
    }
  }
  const float* bias = (z == 0) ? bq : (z == 1) ? bk : bv;
  unsigned short* outp = (z == 0) ? qO : (z == 1) ? kO : vtO;
  int mBase = m0 + wave * 16 + (lane >> 4) * 4;
#pragma unroll
  for (int nb = 0; nb < 4; ++nb) {
    int n = n0 + nb * 16 + lr;
    float bsv = bias[n];
    int h = n >> 6, d = n & 63;
#pragma unroll
    for (int r = 0; r < 4; ++r) {
      int m = mBase + r;
      int b = m >> 11, sIdx = m & 2047;
      unsigned short bits = f2bf(acc[nb][r] + bsv);
      if (z == 2)
        outp[(size_t)((b * HEADS + h) * HEAD_DIM + d) * SEQ + sIdx] = bits;
      else
        outp[(size_t)((b * HEADS + h) * SEQ + sIdx) * HEAD_DIM + d] = bits;
    }
  }
}

// ---------------- K3: flash attention, accumulate into out (holds xn) ------
__global__ __launch_bounds__(256) void attn_kernel(
    const unsigned short* __restrict__ qB, const unsigned short* __restrict__ kB,
    const unsigned short* __restrict__ vtB, float* __restrict__ out) {
  __shared__ unsigned short P_lds[4][16][80];  // +16 pad, rows 160B (16B-aligned)
  int bh = blockIdx.y;
  int b = bh >> 4, h = bh & 15;
  int tid = threadIdx.x, wave = tid >> 6, lane = tid & 63;
  int lr = lane & 15, lk = (lane >> 4) * 8;
  int q0 = blockIdx.x * 64 + wave * 16;
  const unsigned short* qh = qB + (size_t)bh * SEQ * HEAD_DIM;
  const unsigned short* kh = kB + (size_t)bh * SEQ * HEAD_DIM;
  const unsigned short* vh = vtB + (size_t)bh * HEAD_DIM * SEQ;
  bf16x8 qA[2];
#pragma unroll
  for (int ks = 0; ks < 2; ++ks)
    qA[ks] = *(const bf16x8*)(qh + (size_t)(q0 + lr) * HEAD_DIM + ks * 32 + lk);
  float mrun[4], lrun[4];
  f32x4 oAcc[4];
#pragma unroll
  for (int r = 0; r < 4; ++r) { mrun[r] = -1e30f; lrun[r] = 0.f; }
#pragma unroll
  for (int nb = 0; nb < 4; ++nb) oAcc[nb] = (f32x4){0.f, 0.f, 0.f, 0.f};

  for (int kv0 = 0; kv0 < SEQ; kv0 += 64) {
    f32x4 sc[4];
#pragma unroll
    for (int cb = 0; cb < 4; ++cb) {
      sc[cb] = (f32x4){0.f, 0.f, 0.f, 0.f};
#pragma unroll
      for (int ks = 0; ks < 2; ++ks) {
        bf16x8 kF = *(const bf16x8*)(kh + (size_t)(kv0 + cb * 16 + lr) * HEAD_DIM + ks * 32 + lk);
        sc[cb] = __builtin_amdgcn_mfma_f32_16x16x32_bf16(qA[ks], kF, sc[cb], 0, 0, 0);
      }
    }
    float ps[4][4];  // [cb][r]
#pragma unroll
    for (int r = 0; r < 4; ++r) {
      float mt = fmaxf(fmaxf(sc[0][r], sc[1][r]), fmaxf(sc[2][r], sc[3][r])) * 0.125f;
#pragma unroll
      for (int off = 1; off < 16; off <<= 1) mt = fmaxf(mt, __shfl_xor(mt, off));
      float mn = fmaxf(mrun[r], mt);
      float alpha = __expf(mrun[r] - mn);
      mrun[r] = mn;
      float lsum = 0.f;
#pragma unroll
      for (int cb = 0; cb < 4; ++cb) {
        float p = __expf(sc[cb][r] * 0.125f - mn);
        ps[cb][r] = p;
        lsum += p;
      }
#pragma unroll
      for (int off = 1; off < 16; off <<= 1) lsum += __shfl_xor(lsum, off);
      lrun[r] = lrun[r] * alpha + lsum;
#pragma unroll
      for (int nb = 0; nb < 4; ++nb) oAcc[nb][r] *= alpha;
    }
    int qrg = (lane >> 4) * 4;
#pragma unroll
    for (int r = 0; r < 4; ++r)
#pragma unroll
      for (int cb = 0; cb < 4; ++cb)
        P_lds[wave][qrg + r][cb * 16 + lr] = f2bf(ps[cb][r]);
    __syncthreads();
#pragma unroll
    for (int ks = 0; ks < 2; ++ks) {
      bf16x8 pA = *(const bf16x8*)(&P_lds[wave][lr][ks * 32 + lk]);
#pragma unroll
      for (int nb = 0; nb < 4; ++nb) {
        bf16x8 vF = *(const bf16x8*)(vh + (size_t)(nb * 16 + lr) * SEQ + kv0 + ks * 32 + lk);
        oAcc[nb] = __builtin_amdgcn_mfma_f32_16x16x32_bf16(pA, vF, oAcc[nb], 0, 0, 0);
      }
    }
    __syncthreads();
  }
#pragma unroll
  for (int nb = 0; nb < 4; ++nb) {
#pragma unroll
    for (int r = 0; r < 4; ++r) {
      int qrow = q0 + (lane >> 4) * 4 + r;
      size_t idx = ((size_t)(b * SEQ + qrow)) * HIDDEN + h * HEAD_DIM + nb * 16 + lr;
      out[idx] += oAcc[nb][r] / lrun[r];
    }
  }
}

extern "C" void kernel_launch(void* const* d_in, const int* in_sizes, int n_in,
                              void* d_out, int out_size, void* d_ws, size_t ws_size,
                              hipStream_t stream) {
  const float* x     = (const float*)d_in[0];
  const float* Wq    = (const float*)d_in[1];
  const float* bq    = (const float*)d_in[2];
  const float* Wk    = (const float*)d_in[3];
  const float* bk    = (const float*)d_in[4];
  const float* Wv    = (const float*)d_in[5];
  const float* bv    = (const float*)d_in[6];
  const float* gamma = (const float*)d_in[7];
  const float* beta  = (const float*)d_in[8];
  float* out = (float*)d_out;
  char* ws = (char*)d_ws;
  const size_t MB = 1024 * 1024;
  unsigned short* xnb = (unsigned short*)(ws);              // 16 MB  xn bf16 [8192][1024]
  unsigned short* Wt  = (unsigned short*)(ws + 16 * MB);    //  6 MB  3x Wt[n][k] bf16
  unsigned short* qb  = (unsigned short*)(ws + 22 * MB);    // 16 MB  q [b][h][s][d]
  unsigned short* kb  = (unsigned short*)(ws + 38 * MB);    // 16 MB  k [b][h][s][d]
  unsigned short* vtb = (unsigned short*)(ws + 54 * MB);    // 16 MB  v^T [b][h][d][s]

  hipLaunchKernelGGL(wtrans_kernel, dim3(16, 16, 3), dim3(256), 0, stream, Wq, Wk, Wv, Wt);
  hipLaunchKernelGGL(ln_kernel, dim3(BATCH * SEQ), dim3(256), 0, stream, x, gamma, beta, out, xnb);
  hipLaunchKernelGGL(qkv_gemm, dim3(128, 16, 3), dim3(256), 0, stream, xnb, Wt, bq, bk, bv, qb, kb, vtb);
  hipLaunchKernelGGL(attn_kernel, dim3(32, 64), dim3(256), 0, stream, qb, kb, vtb, out);
}

// Round 4
// 335.680 us; speedup vs baseline: 2.8562x; 2.8562x over previous
//
#include <hip/hip_runtime.h>
#include <hip/hip_bf16.h>

#define HIDDEN 1024
#define HEADS 16
#define HEAD_DIM 64
#define SEQ 2048
#define BATCH 4

typedef __attribute__((ext_vector_type(8))) short bf16x8;
typedef __attribute__((ext_vector_type(4))) float f32x4;
typedef __attribute__((ext_vector_type(4))) short short4v;

static __device__ __forceinline__ unsigned short f2bf(float f) {
  union { float f; unsigned u; } u;
  u.f = f;
  unsigned r = u.u + 0x7fffu + ((u.u >> 16) & 1u);  // RTNE
  return (unsigned short)(r >> 16);
}

typedef const __attribute__((address_space(1))) unsigned int* gp1_t;
typedef __attribute__((address_space(3))) unsigned int* lp3_t;
static __device__ __forceinline__ void gload_lds16(const void* g, void* l) {
  __builtin_amdgcn_global_load_lds((gp1_t)g, (lp3_t)l, 16, 0, 0);
}

// ---------------- K0: W [K][N] fp32 -> Wt [N][K] bf16 (3 matrices) ----------
__global__ __launch_bounds__(256) void wtrans_kernel(
    const float* __restrict__ Wq, const float* __restrict__ Wk,
    const float* __restrict__ Wv, unsigned short* __restrict__ Wt) {
  __shared__ float tile[64][65];
  int z = blockIdx.z;
  const float* W = (z == 0) ? Wq : (z == 1) ? Wk : Wv;
  int k0 = blockIdx.x * 64, n0 = blockIdx.y * 64;
  int tid = threadIdx.x;
  int tr = tid >> 4;   // 0..15
  int tc = tid & 15;   // 0..15
#pragma unroll
  for (int p = 0; p < 4; ++p) {
    int kk = p * 16 + tr;
    float4 v = *(const float4*)(W + (size_t)(k0 + kk) * HIDDEN + n0 + tc * 4);
    tile[kk][tc * 4 + 0] = v.x; tile[kk][tc * 4 + 1] = v.y;
    tile[kk][tc * 4 + 2] = v.z; tile[kk][tc * 4 + 3] = v.w;
  }
  __syncthreads();
  unsigned short* op = Wt + (size_t)z * HIDDEN * HIDDEN;
#pragma unroll
  for (int p = 0; p < 4; ++p) {
    int nn = p * 16 + tr;
    short4v o;
    o.x = (short)f2bf(tile[tc * 4 + 0][nn]);
    o.y = (short)f2bf(tile[tc * 4 + 1][nn]);
    o.z = (short)f2bf(tile[tc * 4 + 2][nn]);
    o.w = (short)f2bf(tile[tc * 4 + 3][nn]);
    *(short4v*)(op + (size_t)(n0 + nn) * HIDDEN + k0 + tc * 4) = o;
  }
}

// ---------------- K1: LayerNorm: x -> out (xn fp32 residual), xnb (bf16) ----
__global__ __launch_bounds__(256) void ln_kernel(
    const float* __restrict__ x, const float* __restrict__ gamma,
    const float* __restrict__ beta, float* __restrict__ out,
    unsigned short* __restrict__ xnb) {
  int row = blockIdx.x;
  int tid = threadIdx.x;
  const float4* xr = (const float4*)(x + (size_t)row * HIDDEN);
  float4 v = xr[tid];
  float s = v.x + v.y + v.z + v.w;
  float sq = v.x * v.x + v.y * v.y + v.z * v.z + v.w * v.w;
#pragma unroll
  for (int off = 32; off >= 1; off >>= 1) {
    s += __shfl_xor(s, off);
    sq += __shfl_xor(sq, off);
  }
  __shared__ float red[8];
  int wave = tid >> 6, lane = tid & 63;
  if (lane == 0) { red[wave] = s; red[4 + wave] = sq; }
  __syncthreads();
  s = red[0] + red[1] + red[2] + red[3];
  sq = red[4] + red[5] + red[6] + red[7];
  float mu = s * (1.0f / HIDDEN);
  float var = sq * (1.0f / HIDDEN) - mu * mu;
  float rstd = rsqrtf(var + 1e-5f);
  float4 g = ((const float4*)gamma)[tid];
  float4 bt = ((const float4*)beta)[tid];
  float4 o;
  o.x = (v.x - mu) * rstd * g.x + bt.x;
  o.y = (v.y - mu) * rstd * g.y + bt.y;
  o.z = (v.z - mu) * rstd * g.z + bt.z;
  o.w = (v.w - mu) * rstd * g.w + bt.w;
  ((float4*)(out + (size_t)row * HIDDEN))[tid] = o;
  short4v p;
  p.x = (short)f2bf(o.x); p.y = (short)f2bf(o.y);
  p.z = (short)f2bf(o.z); p.w = (short)f2bf(o.w);
  *((short4v*)(xnb + (size_t)row * HIDDEN) + tid) = p;
}

// ---------------- K2: QKV GEMM, m97 structure: 128x128 tile, BK=32 ----------
// q/k bf16 [b,h,s,d] (q pre-scaled by 0.125), v transposed bf16 [b,h,d,s]
__global__ __launch_bounds__(256) void qkv_gemm(
    const unsigned short* __restrict__ xnb, const unsigned short* __restrict__ Wt,
    const float* __restrict__ bq, const float* __restrict__ bk,
    const float* __restrict__ bv, unsigned short* __restrict__ qO,
    unsigned short* __restrict__ kO, unsigned short* __restrict__ vtO) {
  __shared__ unsigned short As[128 * 32];
  __shared__ unsigned short Bs[128 * 32];
  int z = blockIdx.z;
  int m0 = blockIdx.x * 128;
  int n0 = blockIdx.y * 128;
  int tid = threadIdx.x;
  int wave = tid >> 6, lane = tid & 63;
  int lr = lane & 15, g = lane >> 4;
  const unsigned short* Ab = xnb + (size_t)m0 * HIDDEN;
  const unsigned short* Bb = Wt + (size_t)z * HIDDEN * HIDDEN + (size_t)n0 * HIDDEN;
  // staging source coords (lane covers 16B = 8 shorts)
  int srow0 = wave * 32 + (lane >> 2);
  int srow1 = srow0 + 16;
  int scol = (lane & 3) * 8;
  int wm = wave >> 1, wn = wave & 1;
  f32x4 acc[4][4];
#pragma unroll
  for (int i = 0; i < 4; ++i)
#pragma unroll
    for (int j = 0; j < 4; ++j) acc[i][j] = (f32x4){0.f, 0.f, 0.f, 0.f};

#pragma unroll 1
  for (int k0 = 0; k0 < HIDDEN; k0 += 32) {
    gload_lds16(Ab + (size_t)srow0 * HIDDEN + k0 + scol, &As[wave * 1024]);
    gload_lds16(Ab + (size_t)srow1 * HIDDEN + k0 + scol, &As[wave * 1024 + 512]);
    gload_lds16(Bb + (size_t)srow0 * HIDDEN + k0 + scol, &Bs[wave * 1024]);
    gload_lds16(Bb + (size_t)srow1 * HIDDEN + k0 + scol, &Bs[wave * 1024 + 512]);
    __syncthreads();
    bf16x8 aF[4], bF[4];
#pragma unroll
    for (int mb = 0; mb < 4; ++mb)
      aF[mb] = *(const bf16x8*)&As[(wm * 64 + mb * 16 + lr) * 32 + g * 8];
#pragma unroll
    for (int nb = 0; nb < 4; ++nb)
      bF[nb] = *(const bf16x8*)&Bs[(wn * 64 + nb * 16 + lr) * 32 + g * 8];
#pragma unroll
    for (int mb = 0; mb < 4; ++mb)
#pragma unroll
      for (int nb = 0; nb < 4; ++nb)
        acc[mb][nb] = __builtin_amdgcn_mfma_f32_16x16x32_bf16(aF[mb], bF[nb], acc[mb][nb], 0, 0, 0);
    __syncthreads();
  }
  const float* bias = (z == 0) ? bq : (z == 1) ? bk : bv;
  unsigned short* outp = (z == 0) ? qO : (z == 1) ? kO : vtO;
  float scale = (z == 0) ? 0.125f : 1.0f;
#pragma unroll
  for (int nb = 0; nb < 4; ++nb) {
    int n = n0 + wn * 64 + nb * 16 + lr;
    float bsv = bias[n];
    int h = n >> 6, d = n & 63;
#pragma unroll
    for (int mb = 0; mb < 4; ++mb) {
#pragma unroll
      for (int r = 0; r < 4; ++r) {
        int m = m0 + wm * 64 + mb * 16 + g * 4 + r;
        int b = m >> 11, sIdx = m & 2047;
        unsigned short bits = f2bf((acc[mb][nb][r] + bsv) * scale);
        if (z == 2)
          outp[(size_t)((b * HEADS + h) * HEAD_DIM + d) * SEQ + sIdx] = bits;
        else
          outp[(size_t)((b * HEADS + h) * SEQ + sIdx) * HEAD_DIM + d] = bits;
      }
    }
  }
}

// ---------------- K3: flash attention ---------------------------------------
// Swapped QK^T (lane-local softmax), P via per-wave LDS slab, PV with the
// round-1-verified 16x16x32 fragment paths. No inline asm, no barriers.
__global__ __launch_bounds__(256) void attn_kernel(
    const unsigned short* __restrict__ qB, const unsigned short* __restrict__ kB,
    const unsigned short* __restrict__ vtB, float* __restrict__ out) {
  __shared__ unsigned short P_lds[4][2][16][72];  // [wave][qb][q][k] stride 144B
  // XCD-aware bijective swizzle: all 16 q-tiles of one head on one XCD.
  int orig = blockIdx.y * gridDim.x + blockIdx.x;  // nwg = 16*64 = 1024
  int swz = (orig & 7) * 128 + (orig >> 3);
  int bx = swz & 15;   // q-tile
  int by = swz >> 4;   // bh
  int b = by >> 4, h = by & 15;
  int tid = threadIdx.x, wave = tid >> 6, lane = tid & 63;
  int lr = lane & 15;   // q-col within 16-block (softmax state lives here)
  int g = lane >> 4;    // 0..3
  int q0 = bx * 128 + wave * 32;
  const unsigned short* qh = qB + (size_t)by * SEQ * HEAD_DIM;
  const unsigned short* kh = kB + (size_t)by * SEQ * HEAD_DIM;
  const unsigned short* vh = vtB + (size_t)by * HEAD_DIM * SEQ;

  bf16x8 qA[2][2];
#pragma unroll
  for (int qb = 0; qb < 2; ++qb)
#pragma unroll
    for (int ks = 0; ks < 2; ++ks)
      qA[qb][ks] = *(const bf16x8*)(qh + (size_t)(q0 + qb * 16 + lr) * HEAD_DIM + ks * 32 + g * 8);

  f32x4 oAcc[2][4];  // [qb][nb]: D rows q=g*4+r (within qb 16-block), col d=nb*16+lr
#pragma unroll
  for (int qb = 0; qb < 2; ++qb)
#pragma unroll
    for (int nb = 0; nb < 4; ++nb) oAcc[qb][nb] = (f32x4){0.f, 0.f, 0.f, 0.f};
  float mrun[2] = {-1e30f, -1e30f};
  float lrun[2] = {0.f, 0.f};

#pragma unroll 1
  for (int kv0 = 0; kv0 < SEQ; kv0 += 64) {
    // K fragments (shared across both q sub-blocks)
    bf16x8 kF[4][2];
#pragma unroll
    for (int cb = 0; cb < 4; ++cb)
#pragma unroll
      for (int ks = 0; ks < 2; ++ks)
        kF[cb][ks] = *(const bf16x8*)(kh + (size_t)(kv0 + cb * 16 + lr) * HEAD_DIM + ks * 32 + g * 8);
    // QK^T swapped: D[k][q]: lane owns P[q=lr][k=cb*16+g*4+r]
#pragma unroll
    for (int qb = 0; qb < 2; ++qb) {
      f32x4 sc[4];
#pragma unroll
      for (int cb = 0; cb < 4; ++cb) {
        f32x4 t = (f32x4){0.f, 0.f, 0.f, 0.f};
        t = __builtin_amdgcn_mfma_f32_16x16x32_bf16(kF[cb][0], qA[qb][0], t, 0, 0, 0);
        t = __builtin_amdgcn_mfma_f32_16x16x32_bf16(kF[cb][1], qA[qb][1], t, 0, 0, 0);
        sc[cb] = t;
      }
      // lane-local softmax for q=lr
      float mt = sc[0][0];
#pragma unroll
      for (int cb = 0; cb < 4; ++cb)
#pragma unroll
        for (int r = 0; r < 4; ++r) mt = fmaxf(mt, sc[cb][r]);
      mt = fmaxf(mt, __shfl_xor(mt, 16));
      mt = fmaxf(mt, __shfl_xor(mt, 32));
      float mnOld = mrun[qb];
      bool need = !__all(mt <= mnOld);
      float mn = mnOld;
      if (need) {
        mn = fmaxf(mnOld, mt);
        float alpha = __expf(mnOld - mn);
        mrun[qb] = mn;
        lrun[qb] *= alpha;
        // redistribute alpha to O-row owners (row q = g*4+r lives on lane g*4+r)
        float aR[4];
#pragma unroll
        for (int r = 0; r < 4; ++r) aR[r] = __shfl(alpha, g * 4 + r);
#pragma unroll
        for (int nb = 0; nb < 4; ++nb)
#pragma unroll
          for (int r = 0; r < 4; ++r) oAcc[qb][nb][r] *= aR[r];
      }
      float p[4][4];
      float lsum = 0.f;
#pragma unroll
      for (int cb = 0; cb < 4; ++cb)
#pragma unroll
        for (int r = 0; r < 4; ++r) {
          float e = __expf(sc[cb][r] - mn);
          p[cb][r] = e;
          lsum += e;
        }
      lsum += __shfl_xor(lsum, 16);
      lsum += __shfl_xor(lsum, 32);
      lrun[qb] += lsum;
      // P -> LDS (bf16), layout [q=lr][k], u32 stores (2-way free banks)
#pragma unroll
      for (int cb = 0; cb < 4; ++cb)
#pragma unroll
        for (int i = 0; i < 2; ++i) {
          unsigned u = (unsigned)f2bf(p[cb][2 * i]) | ((unsigned)f2bf(p[cb][2 * i + 1]) << 16);
          *(unsigned*)&P_lds[wave][qb][lr][cb * 16 + g * 4 + 2 * i] = u;
        }
    }
    // PV: mfma(P_A, V_B) -> D[q][d], rows q=g*4+r, col d=lr (round-1 verified)
    bf16x8 pA[2][2];
#pragma unroll
    for (int qb = 0; qb < 2; ++qb)
#pragma unroll
      for (int ks = 0; ks < 2; ++ks)
        pA[qb][ks] = *(const bf16x8*)&P_lds[wave][qb][lr][ks * 32 + g * 8];
#pragma unroll
    for (int nb = 0; nb < 4; ++nb) {
#pragma unroll
      for (int ks = 0; ks < 2; ++ks) {
        bf16x8 vF = *(const bf16x8*)(vh + (size_t)(nb * 16 + lr) * SEQ + kv0 + ks * 32 + g * 8);
#pragma unroll
        for (int qb = 0; qb < 2; ++qb)
          oAcc[qb][nb] = __builtin_amdgcn_mfma_f32_16x16x32_bf16(pA[qb][ks], vF, oAcc[qb][nb], 0, 0, 0);
      }
    }
  }
  // epilogue: out[q][h*64+d] += O[q][d]/l[q]; q = q0+qb*16+g*4+r, d = nb*16+lr
#pragma unroll
  for (int qb = 0; qb < 2; ++qb) {
    float linv = 1.0f / lrun[qb];
    float lR[4];
#pragma unroll
    for (int r = 0; r < 4; ++r) lR[r] = __shfl(linv, g * 4 + r);
#pragma unroll
    for (int r = 0; r < 4; ++r) {
      int qrow = q0 + qb * 16 + g * 4 + r;
      float* orow = out + ((size_t)b * SEQ + qrow) * HIDDEN + h * HEAD_DIM;
#pragma unroll
      for (int nb = 0; nb < 4; ++nb)
        orow[nb * 16 + lr] += oAcc[qb][nb][r] * lR[r];
    }
  }
}

extern "C" void kernel_launch(void* const* d_in, const int* in_sizes, int n_in,
                              void* d_out, int out_size, void* d_ws, size_t ws_size,
                              hipStream_t stream) {
  const float* x     = (const float*)d_in[0];
  const float* Wq    = (const float*)d_in[1];
  const float* bq    = (const float*)d_in[2];
  const float* Wk    = (const float*)d_in[3];
  const float* bk    = (const float*)d_in[4];
  const float* Wv    = (const float*)d_in[5];
  const float* bv    = (const float*)d_in[6];
  const float* gamma = (const float*)d_in[7];
  const float* beta  = (const float*)d_in[8];
  float* out = (float*)d_out;
  char* ws = (char*)d_ws;
  const size_t MB = 1024 * 1024;
  unsigned short* xnb = (unsigned short*)(ws);              // 16 MB  xn bf16 [8192][1024]
  unsigned short* Wt  = (unsigned short*)(ws + 16 * MB);    //  6 MB  3x Wt[n][k] bf16
  unsigned short* qb  = (unsigned short*)(ws + 22 * MB);    // 16 MB  q [b][h][s][d] (pre-scaled 1/8)
  unsigned short* kb  = (unsigned short*)(ws + 38 * MB);    // 16 MB  k [b][h][s][d]
  unsigned short* vtb = (unsigned short*)(ws + 54 * MB);    // 16 MB  v^T [b][h][d][s]

  hipLaunchKernelGGL(wtrans_kernel, dim3(16, 16, 3), dim3(256), 0, stream, Wq, Wk, Wv, Wt);
  hipLaunchKernelGGL(ln_kernel, dim3(BATCH * SEQ), dim3(256), 0, stream, x, gamma, beta, out, xnb);
  hipLaunchKernelGGL(qkv_gemm, dim3(64, 8, 3), dim3(256), 0, stream, xnb, Wt, bq, bk, bv, qb, kb, vtb);
  hipLaunchKernelGGL(attn_kernel, dim3(16, 64), dim3(256), 0, stream, qb, kb, vtb, out);
}